// Round 3
// baseline (6285.706 us; speedup 1.0000x reference)
//
#include <hip/hip_runtime.h>
#include <stdint.h>

#define MDIM 4096
#define KDIM 4096
#define NDIM 11008

// Diagnostic oracle: pure fp32 VALU GEMM, no bf16, no MFMA.
// 64x64 output tile per 256-thread block; each thread computes a 4x4
// register tile strided by 16. Dequant is written exactly as the reference:
// w = ((float)q - (float)zp) * s with group g = k / 128.
__global__ __launch_bounds__(256) void int4_gemm_valu(
    const float* __restrict__ A, const int* __restrict__ Q,
    const float* __restrict__ S, const int* __restrict__ Z,
    const float* __restrict__ bias, float* __restrict__ out)
{
    __shared__ float sA[64][33];   // [m][k], +1 pad
    __shared__ float sB[32][65];   // [k][n], +1 pad

    const int bm = blockIdx.x / (NDIM / 64);
    const int bn = blockIdx.x % (NDIM / 64);
    const int m0 = bm * 64, n0 = bn * 64;

    const int t  = threadIdx.x;
    const int tx = t & 15;         // output col within tile (mod 16)
    const int ty = t >> 4;         // output row within tile (mod 16)

    // A staging: row = t>>2 (0..63), k cols = (t&3)*8 .. +7  (two float4)
    const int arow = t >> 2;
    const int acol = (t & 3) * 8;
    // B staging: n pair = (t&31)*2 (0..62), k rows = (t>>5)*4 .. +3
    const int bnn  = (t & 31) * 2;
    const int bkq  = t >> 5;

    float acc[4][4] = {};

    for (int kt = 0; kt < KDIM / 32; ++kt) {
        const int k0 = kt * 32;
        const int g  = kt >> 2;    // k-group: 32*kt/128

        __syncthreads();

        // ---- stage A tile: 64 x 32 fp32, coalesced float4 loads ----
        {
            const float* ap = A + (size_t)(m0 + arow) * KDIM + k0 + acol;
            float4 v0 = *(const float4*)(ap);
            float4 v1 = *(const float4*)(ap + 4);
            sA[arow][acol + 0] = v0.x;  sA[arow][acol + 1] = v0.y;
            sA[arow][acol + 2] = v0.z;  sA[arow][acol + 3] = v0.w;
            sA[arow][acol + 4] = v1.x;  sA[arow][acol + 5] = v1.y;
            sA[arow][acol + 6] = v1.z;  sA[arow][acol + 7] = v1.w;
        }

        // ---- stage B tile: 32 x 64 dequantized fp32 ----
        {
            float2 sc = *(const float2*)(S + (size_t)g * NDIM + n0 + bnn);
            int2   zp = *(const int2*)  (Z + (size_t)g * NDIM + n0 + bnn);
            #pragma unroll
            for (int j = 0; j < 4; ++j) {
                const int kk = bkq * 4 + j;
                int2 q = *(const int2*)(Q + (size_t)(k0 + kk) * NDIM + n0 + bnn);
                sB[kk][bnn    ] = ((float)q.x - (float)zp.x) * sc.x;
                sB[kk][bnn + 1] = ((float)q.y - (float)zp.y) * sc.y;
            }
        }

        __syncthreads();

        // ---- inner product ----
        #pragma unroll 8
        for (int kk = 0; kk < 32; ++kk) {
            float a0 = sA[ty     ][kk];
            float a1 = sA[ty + 16][kk];
            float a2 = sA[ty + 32][kk];
            float a3 = sA[ty + 48][kk];
            float b0 = sB[kk][tx     ];
            float b1 = sB[kk][tx + 16];
            float b2 = sB[kk][tx + 32];
            float b3 = sB[kk][tx + 48];
            acc[0][0] += a0 * b0;  acc[0][1] += a0 * b1;
            acc[0][2] += a0 * b2;  acc[0][3] += a0 * b3;
            acc[1][0] += a1 * b0;  acc[1][1] += a1 * b1;
            acc[1][2] += a1 * b2;  acc[1][3] += a1 * b3;
            acc[2][0] += a2 * b0;  acc[2][1] += a2 * b1;
            acc[2][2] += a2 * b2;  acc[2][3] += a2 * b3;
            acc[3][0] += a3 * b0;  acc[3][1] += a3 * b1;
            acc[3][2] += a3 * b2;  acc[3][3] += a3 * b3;
        }
    }

    // ---- epilogue ----
    #pragma unroll
    for (int u = 0; u < 4; ++u) {
        #pragma unroll
        for (int v = 0; v < 4; ++v) {
            const int m = m0 + ty + 16 * u;
            const int n = n0 + tx + 16 * v;
            out[(size_t)m * NDIM + n] = acc[u][v] + bias[n];
        }
    }
}

extern "C" void kernel_launch(void* const* d_in, const int* in_sizes, int n_in,
                              void* d_out, int out_size, void* d_ws, size_t ws_size,
                              hipStream_t stream) {
    const float* A    = (const float*)d_in[0];
    const int*   Q    = (const int*)d_in[1];
    const float* S    = (const float*)d_in[2];
    const int*   Z    = (const int*)d_in[3];
    const float* bias = (const float*)d_in[4];
    float* out = (float*)d_out;

    const int grid = (MDIM / 64) * (NDIM / 64);   // 64 * 172 = 11008
    int4_gemm_valu<<<dim3(grid), dim3(256), 0, stream>>>(A, Q, S, Z, bias, out);
}

// Round 4
// 2414.448 us; speedup vs baseline: 2.6034x; 2.6034x over previous
//
#include <hip/hip_runtime.h>
#include <hip/hip_bf16.h>
#include <stdint.h>

#define MDIM 4096
#define KDIM 4096
#define NDIM 11008

typedef __bf16 bf16x8 __attribute__((ext_vector_type(8)));
typedef float  f32x4  __attribute__((ext_vector_type(4)));

// Oracle staging (proven round 3) + MFMA inner product (under test).
// 64x64 tile, 256 threads = 4 waves in 2x2; each wave: 32x32 via 2x2
// mfma_f32_16x16x32_bf16 tiles per 32-k step.
__global__ __launch_bounds__(256) void int4_gemm_mfma(
    const float* __restrict__ A, const int* __restrict__ Q,
    const float* __restrict__ S, const int* __restrict__ Z,
    const float* __restrict__ bias, float* __restrict__ out)
{
    __shared__ float sA[64][36];   // [m][k], padded pitch (16B-aligned octets)
    __shared__ float sB[32][68];   // [k][n], padded pitch

    const int bm = blockIdx.x / (NDIM / 64);
    const int bn = blockIdx.x % (NDIM / 64);
    const int m0 = bm * 64, n0 = bn * 64;

    const int t    = threadIdx.x;
    const int lane = t & 63;
    const int wave = t >> 6;
    const int wm   = (wave >> 1) * 32;   // wave quadrant
    const int wn   = (wave & 1) * 32;
    const int fr   = lane & 15;          // A row / B col within 16-tile
    const int fq   = lane >> 4;          // k-octet: k = fq*8 + e

    // staging maps — identical to the passing oracle
    const int arow = t >> 2;             // 0..63
    const int acol = (t & 3) * 8;        // 0,8,16,24
    const int bnn  = (t & 31) * 2;       // 0..62
    const int bkq  = t >> 5;             // 0..7 -> k rows bkq*4..+3

    f32x4 acc[2][2];
    #pragma unroll
    for (int i = 0; i < 2; ++i)
        #pragma unroll
        for (int j = 0; j < 2; ++j)
            #pragma unroll
            for (int r = 0; r < 4; ++r)
                acc[i][j][r] = 0.0f;

    for (int kt = 0; kt < KDIM / 32; ++kt) {
        const int k0 = kt * 32;
        const int g  = kt >> 2;

        __syncthreads();

        // ---- stage A tile: 64 x 32 fp32 (oracle-identical) ----
        {
            const float* ap = A + (size_t)(m0 + arow) * KDIM + k0 + acol;
            float4 v0 = *(const float4*)(ap);
            float4 v1 = *(const float4*)(ap + 4);
            sA[arow][acol + 0] = v0.x;  sA[arow][acol + 1] = v0.y;
            sA[arow][acol + 2] = v0.z;  sA[arow][acol + 3] = v0.w;
            sA[arow][acol + 4] = v1.x;  sA[arow][acol + 5] = v1.y;
            sA[arow][acol + 6] = v1.z;  sA[arow][acol + 7] = v1.w;
        }

        // ---- stage B tile: 32 x 64 dequant fp32 (oracle-identical) ----
        {
            float2 sc = *(const float2*)(S + (size_t)g * NDIM + n0 + bnn);
            int2   zp = *(const int2*)  (Z + (size_t)g * NDIM + n0 + bnn);
            #pragma unroll
            for (int j = 0; j < 4; ++j) {
                const int kk = bkq * 4 + j;
                int2 q = *(const int2*)(Q + (size_t)(k0 + kk) * NDIM + n0 + bnn);
                sB[kk][bnn    ] = ((float)q.x - (float)zp.x) * sc.x;
                sB[kk][bnn + 1] = ((float)q.y - (float)zp.y) * sc.y;
            }
        }

        __syncthreads();

        // ---- fragments (per documented contract) + MFMA ----
        // A operand: lane holds A[m = 16*i + fr][k = fq*8 + e], e=0..7
        bf16x8 aF[2], bF[2];
        #pragma unroll
        for (int i = 0; i < 2; ++i) {
            const float* ap = &sA[wm + 16 * i + fr][fq * 8];
            float4 u0 = *(const float4*)(ap);
            float4 u1 = *(const float4*)(ap + 4);
            bf16x8 v;
            v[0] = (__bf16)u0.x; v[1] = (__bf16)u0.y;
            v[2] = (__bf16)u0.z; v[3] = (__bf16)u0.w;
            v[4] = (__bf16)u1.x; v[5] = (__bf16)u1.y;
            v[6] = (__bf16)u1.z; v[7] = (__bf16)u1.w;
            aF[i] = v;
        }
        // B operand: lane holds B[k = fq*8 + e][n = 16*j + fr], e=0..7
        #pragma unroll
        for (int j = 0; j < 2; ++j) {
            bf16x8 v;
            #pragma unroll
            for (int e = 0; e < 8; ++e)
                v[e] = (__bf16)sB[fq * 8 + e][wn + 16 * j + fr];
            bF[j] = v;
        }

        #pragma unroll
        for (int i = 0; i < 2; ++i)
            #pragma unroll
            for (int j = 0; j < 2; ++j)
                acc[i][j] = __builtin_amdgcn_mfma_f32_16x16x32_bf16(
                                aF[i], bF[j], acc[i][j], 0, 0, 0);
    }

    // ---- epilogue: C/D col = lane&15, row = (lane>>4)*4 + r ----
    #pragma unroll
    for (int i = 0; i < 2; ++i) {
        #pragma unroll
        for (int r = 0; r < 4; ++r) {
            const int m = m0 + wm + 16 * i + fq * 4 + r;
            #pragma unroll
            for (int j = 0; j < 2; ++j) {
                const int n = n0 + wn + 16 * j + fr;
                out[(size_t)m * NDIM + n] = acc[i][j][r] + bias[n];
            }
        }
    }
}

extern "C" void kernel_launch(void* const* d_in, const int* in_sizes, int n_in,
                              void* d_out, int out_size, void* d_ws, size_t ws_size,
                              hipStream_t stream) {
    const float* A    = (const float*)d_in[0];
    const int*   Q    = (const int*)d_in[1];
    const float* S    = (const float*)d_in[2];
    const int*   Z    = (const int*)d_in[3];
    const float* bias = (const float*)d_in[4];
    float* out = (float*)d_out;

    const int grid = (MDIM / 64) * (NDIM / 64);   // 11008 blocks
    int4_gemm_mfma<<<dim3(grid), dim3(256), 0, stream>>>(A, Q, S, Z, bias, out);
}